// Round 15
// baseline (1514.291 us; speedup 1.0000x reference)
//
#include <hip/hip_runtime.h>
#include <hip/hip_bf16.h>
#include <hip/hip_cooperative_groups.h>

// PointCloudNetPersistencePrediction — round 15: persistent cooperative kernel.
// R9-R14: applies pinned at ~15.4us while DS-count, conflicts, pk-count,
// scheduling and occupancy-split changes were all flat -> ~6-9us of each
// apply is per-kernel structural overhead (launch+ramp+X-restage+drain), not
// issue work. Fix: ONE kernel, 256 blocks x 1024 thr (1/CU), block owns a
// fixed (pair,128-row) tile; X staged to LDS once; ihd in registers; R12 hot
// loop per step; grid.sync() between applies; buildU folded in.

#define NN 2048
#define NPAIR 16

namespace cg = cooperative_groups;

typedef _Float16 half8 __attribute__((ext_vector_type(8)));
typedef _Float16 f16x2 __attribute__((ext_vector_type(2)));
typedef float f32x4 __attribute__((ext_vector_type(4)));

extern "C" __device__ f16x2 __ocml_exp2_2f16(f16x2);   // packed v_exp_f16

#define C2F 0.28853900817779268f   //  0.2 * log2(e)
#define CWF -0.14426950408889634f  // -0.1 * log2(e)
#define NL2T 3.3219280948873623f   // -log2(0.1); qi' = qi + NL2T

// ---- init: Xs fp32 [p][i][{x,y,z,q}]; XT fp16 [p][16][2048], row3 = ones ----
__global__ __launch_bounds__(256) void init_k(const float* __restrict__ pc,
                                              const float* __restrict__ alphas,
                                              float* __restrict__ Xs,
                                              _Float16* __restrict__ XT) {
    int gid = blockIdx.x * 256 + threadIdx.x;
    if (gid >= NPAIR * NN) return;
    int p = gid >> 11, i = gid & (NN - 1);
    int b = p >> 2, k = p & 3;
    const float* pcr = pc + ((size_t)b * NN + i) * 3;
    const float* al  = alphas + k * 3;
    float x = pcr[0] * al[0], y = pcr[1] * al[1], z = pcr[2] * al[2];
    float4 o; o.x = x; o.y = y; o.z = z; o.w = CWF * (x * x + y * y + z * z);
    ((float4*)Xs)[gid] = o;
    _Float16* xt = XT + (size_t)p * 16 * NN + i;
    xt[0 * NN] = (_Float16)x;
    xt[1 * NN] = (_Float16)y;
    xt[2 * NN] = (_Float16)z;
    xt[3 * NN] = (_Float16)1.0f;          // ones column -> deg via MFMA
#pragma unroll
    for (int n = 4; n < 16; ++n) xt[n * NN] = (_Float16)0.f;
}

// ---- pack_k: Xp16[p][e] = {x2,y2,z2,q2} fp16 pairs of rows (2e, 2e+1) ----
__global__ __launch_bounds__(256) void pack_k(const float* __restrict__ Xs,
                                              float* __restrict__ Xp) {
    int gid = blockIdx.x * 256 + threadIdx.x;      // p*1024 + e
    if (gid >= NPAIR * 1024) return;
    float4 a = ((const float4*)Xs)[2 * gid];
    float4 b = ((const float4*)Xs)[2 * gid + 1];
    union { f16x2 h[4]; float4 f; } o;
    o.h[0] = (f16x2){(_Float16)a.x, (_Float16)b.x};
    o.h[1] = (f16x2){(_Float16)a.y, (_Float16)b.y};
    o.h[2] = (f16x2){(_Float16)a.z, (_Float16)b.z};
    o.h[3] = (f16x2){(_Float16)a.w, (_Float16)b.w};
    ((float4*)Xp)[gid] = o.f;
}

// ---- persistent kernel: both banks' 16 applies + buildU, grid.sync between.
// Block = (p, 128-row tile). 16 waves = mg(2) x kg(8). Lane: s=4 subtiles.
// LDS: [0..4095] packed X (persists), [4096..12287] reduce scratch. 48 KB.
__global__ __launch_bounds__(1024, 4) void persist_k(const float* __restrict__ Xs,
                                                     const float* __restrict__ Xp,
                                                     const _Float16* __restrict__ XT,
                                                     _Float16* __restrict__ UT,
                                                     _Float16* __restrict__ pA,
                                                     _Float16* __restrict__ pB,
                                                     float* __restrict__ LT1,
                                                     float* __restrict__ LT2) {
    __shared__ __align__(16) float smem[12288];
    cg::grid_group grid = cg::this_grid();
    const int tid  = threadIdx.x;
    const int lane = tid & 63;
    const int wv   = tid >> 6;
    const int p    = blockIdx.x >> 4;
    const int m0   = (blockIdx.x & 15) << 7;       // tile base row (128/block)
    const int idx16 = lane & 15, quad = lane >> 4;
    const int mg = wv & 1, kg = wv >> 1;

    // stage packed X[p] into LDS once (1024 float4, 1 per thread)
    ((float4*)smem)[tid] = ((const float4*)(Xp + (size_t)p * 4096))[tid];
    __syncthreads();

    // per-lane row constants (fixed for the whole kernel: rows are fixed)
    f16x2 qi2[4], xx2[4], xy2[4], xz2[4];
#pragma unroll
    for (int s = 0; s < 4; ++s) {
        float4 v = *(const float4*)(Xs + ((size_t)p * NN + m0 + mg * 64 + s * 16 + idx16) * 4);
        _Float16 q = (_Float16)(v.w + NL2T);
        _Float16 x = (_Float16)(C2F * v.x);
        _Float16 y = (_Float16)(C2F * v.y);
        _Float16 z = (_Float16)(C2F * v.z);
        qi2[s] = (f16x2){q, q}; xx2[s] = (f16x2){x, x};
        xy2[s] = (f16x2){y, y}; xz2[s] = (f16x2){z, z};
    }
    const f16x2 SC2 = (f16x2){(_Float16)32768.f, (_Float16)32768.f};

    float ihE[2] = {0.f, 0.f};     // 0.1*ih for this thread's 2 epilogue rows

    for (int bank = 0; bank < 2; ++bank) {
        const _Float16* cur = bank ? (const _Float16*)UT : XT;
        float* LT = bank ? LT2 : LT1;
        int slot = 0;
        for (int step = 1; step <= 16; ++step) {
            _Float16* out = (step & 1) ? pA : pB;
            const bool sv = (step & (step - 1)) == 0;   // 1,2,4,8,16
            const _Float16* bp = cur + ((size_t)p * 16 + idx16) * NN + kg * 256 + quad * 8;
            f32x4 acc[4] = {{0.f,0.f,0.f,0.f},{0.f,0.f,0.f,0.f},
                            {0.f,0.f,0.f,0.f},{0.f,0.f,0.f,0.f}};
            for (int kc = 0; kc < 8; ++kc) {
                const int pb = kg * 128 + kc * 16 + quad * 4;
                half8 bf = *(const half8*)(bp + kc * 32);
                union { f16x2 h2[4]; half8 h8; } af[4];
#pragma unroll
                for (int jp = 0; jp < 4; ++jp) {
                    union { float4 f; f16x2 h[4]; } e;
                    e.f = ((const float4*)smem)[pb + jp];
#pragma unroll
                    for (int s = 0; s < 4; ++s) {
                        f16x2 tv = qi2[s] + e.h[3];
                        tv = __builtin_elementwise_fma(xx2[s], e.h[0], tv);
                        tv = __builtin_elementwise_fma(xy2[s], e.h[1], tv);
                        tv = __builtin_elementwise_fma(xz2[s], e.h[2], tv);
                        f16x2 u = __builtin_elementwise_min(tv, tv * SC2);
                        af[s].h2[jp] = __ocml_exp2_2f16(u);   // = 10*w
                    }
                }
#pragma unroll
                for (int s = 0; s < 4; ++s)
                    acc[s] = __builtin_amdgcn_mfma_f32_16x16x32_f16(af[s].h8, bf, acc[s], 0, 0, 0);
            }
            // epilogue: two passes over the mg halves through 32 KB red region
#pragma unroll
            for (int pass = 0; pass < 2; ++pass) {
                __syncthreads();
                if (mg == pass) {
#pragma unroll
                    for (int s = 0; s < 4; ++s)
                        *(f32x4*)&smem[4096 + kg * 1024 + s * 256 + lane * 4] = acc[s];
                }
                __syncthreads();
                const int n = tid & 15, rloc = tid >> 4;        // rloc 0..63
                const int s2 = rloc >> 4, mloc = rloc & 15;
                const int base = 4096 + s2 * 256 + (mloc >> 2) * 64 + (mloc & 3);
                float sum = 0.f;                                 // = 10*(W@B)
#pragma unroll
                for (int g = 0; g < 8; ++g) sum += smem[base + g * 1024 + n * 4];
                const int row = m0 + pass * 64 + rloc;
                if (bank == 0 && step == 1) {
                    float deg10 = 0.f;                           // = 10*deg
#pragma unroll
                    for (int g = 0; g < 8; ++g) deg10 += smem[base + g * 1024 + 12];
                    ihE[pass] = 0.5f / deg10;                    // = 0.1*(0.5/deg)
                }
                float cv = (float)cur[((size_t)p * 16 + n) * NN + row];
                float o = 0.5f * cv + ihE[pass] * sum;
                out[((size_t)p * 16 + n) * NN + row] = (_Float16)o;
                if (sv) LT[(((size_t)p * 5 + slot) * 16 + n) * NN + row] = o;
            }
            grid.sync();
            cur = out;
            if (sv) ++slot;
        }
        if (bank == 0) {
            // buildU for this block's rows (levels at these rows are block-local)
            if (tid < 128) {
                const int m = m0 + tid;
                float4 xr = ((const float4*)Xs)[(size_t)p * NN + m];
                float prev[3] = {xr.x, xr.y, xr.z};
                _Float16* ut = UT + (size_t)p * 16 * NN + m;
#pragma unroll
                for (int jw = 0; jw < 4; ++jw)
#pragma unroll
                    for (int c = 0; c < 3; ++c) {
                        float nx = LT1[(((size_t)p * 5 + jw) * 16 + c) * NN + m];
                        ut[(3 * jw + c) * NN] = (_Float16)fabsf(prev[c] - nx);
                        prev[c] = nx;
                    }
#pragma unroll
                for (int n2 = 12; n2 < 16; ++n2) ut[n2 * NN] = (_Float16)0.f;
            }
            grid.sync();
        }
    }
}

// ---- final mean over N of 48 features (levels [p][t][n][m]) ----
__global__ __launch_bounds__(64) void reduce_k(const float* __restrict__ Xs,
                                               const float* __restrict__ LT1,
                                               const float* __restrict__ LT2,
                                               float* __restrict__ out) {
    int f = blockIdx.x, p = blockIdx.y, lane = threadIdx.x;
    const float* l1 = LT1 + (size_t)p * 5 * 16 * NN;
    const float* l2 = LT2 + (size_t)p * 5 * 16 * NN;
    float s = 0.f;
    for (int m = lane; m < NN; m += 64) {
        float v;
        if (f < 3) {
            v = l1[((size_t)4 * 16 + f) * NN + m];
        } else if (f < 18) {
            int j = (f - 3) / 3, c = (f - 3) % 3;
            float a = (j == 0) ? Xs[((size_t)p * NN + m) * 4 + c]
                               : l1[((size_t)(j - 1) * 16 + c) * NN + m];
            float b = l1[((size_t)j * 16 + c) * NN + m];
            v = fabsf(a - b);
        } else {
            int gg = f - 18, j2, uc;
            if (gg < 3)       { j2 = 1; uc = gg; }
            else if (gg < 9)  { j2 = 2; uc = gg - 3; }
            else if (gg < 18) { j2 = 3; uc = gg - 9; }
            else              { j2 = 4; uc = gg - 18; }
            v = fabsf(l2[((size_t)(j2 - 1) * 16 + uc) * NN + m]
                    - l2[((size_t)j2 * 16 + uc) * NN + m]);
        }
        s += v;
    }
#pragma unroll
    for (int off = 32; off > 0; off >>= 1) s += __shfl_down(s, off, 64);
    if (lane == 0) out[p * 48 + f] = s * (1.0f / NN);
}

extern "C" void kernel_launch(void* const* d_in, const int* in_sizes, int n_in,
                              void* d_out, int out_size, void* d_ws, size_t ws_size,
                              hipStream_t stream) {
    const float* pc     = (const float*)d_in[0];
    const float* alphas = (const float*)d_in[1];
    float* outp = (float*)d_out;

    char* base = (char*)d_ws;
    size_t off = 0;
    auto carve = [&](size_t bytes) -> void* {
        void* r = base + off;
        off = (off + bytes + 255) & ~(size_t)255;
        return r;
    };
    float*     Xs  = (float*)carve((size_t)NPAIR * NN * 4 * sizeof(float));
    float*     Xp  = (float*)carve((size_t)NPAIR * 1024 * 4 * sizeof(float));
    _Float16*  XT  = (_Float16*)carve((size_t)NPAIR * 16 * NN * 2);
    _Float16*  UT  = (_Float16*)carve((size_t)NPAIR * 16 * NN * 2);
    _Float16*  pA  = (_Float16*)carve((size_t)NPAIR * 16 * NN * 2);
    _Float16*  pB  = (_Float16*)carve((size_t)NPAIR * 16 * NN * 2);
    float*     LT1 = (float*)carve((size_t)NPAIR * 5 * 16 * NN * sizeof(float));
    float*     LT2 = (float*)carve((size_t)NPAIR * 5 * 16 * NN * sizeof(float));

    init_k<<<dim3((NPAIR * NN) / 256), 256, 0, stream>>>(pc, alphas, Xs, XT);
    pack_k<<<dim3((NPAIR * 1024) / 256), 256, 0, stream>>>(Xs, Xp);

    void* kargs[] = {(void*)&Xs, (void*)&Xp, (void*)&XT, (void*)&UT,
                     (void*)&pA, (void*)&pB, (void*)&LT1, (void*)&LT2};
    hipLaunchCooperativeKernel((void*)persist_k, dim3(256), dim3(1024),
                               kargs, 0, stream);

    reduce_k<<<dim3(48, NPAIR), 64, 0, stream>>>(Xs, LT1, LT2, outp);
}

// Round 18
// 483.657 us; speedup vs baseline: 3.1309x; 3.1309x over previous
//
#include <hip/hip_runtime.h>
#include <hip/hip_bf16.h>

// PointCloudNetPersistencePrediction — round 17b: compile fix (Xp is fp16*).
// R15: grid.sync ~35us. R16: DIY LLC-sync incorrect -> reverted to R14 base.
// Model (R9-R15): apply = ~6us compute + ~9.5us kernel-boundary; boundary is
// the lever. Bank2 needs only levels t<=8; bank1 s9-16 feeds only reduce_k.
// => merge bank1 s9-16 with bank2 s1-8: ONE w-eval pass feeds BOTH banks'
// MFMAs (evals shared; merged ~1.15x single compute). Launches 33 -> 25
// (+init/pack fused). All kernel bodies are the R14-proven structure.

#define NN 2048
#define NPAIR 16

typedef _Float16 half8 __attribute__((ext_vector_type(8)));
typedef _Float16 f16x2 __attribute__((ext_vector_type(2)));
typedef float f32x4 __attribute__((ext_vector_type(4)));

extern "C" __device__ f16x2 __ocml_exp2_2f16(f16x2);   // packed v_exp_f16

#define C2F 0.28853900817779268f   //  0.2 * log2(e)
#define CWF -0.14426950408889634f  // -0.1 * log2(e)
#define NL2T 3.3219280948873623f   // -log2(0.1); qi' = qi + NL2T

// ---- init+pack fused: Xs fp32 [p][i][{x,y,z,q}]; XT fp16 [p][16][2048]
//      (row3 = ones -> deg via MFMA); Xp packed fp16 j-pair entries ----
__global__ __launch_bounds__(256) void initpack_k(const float* __restrict__ pc,
                                                  const float* __restrict__ alphas,
                                                  float* __restrict__ Xs,
                                                  _Float16* __restrict__ XT,
                                                  _Float16* __restrict__ Xp) {
    int gid = blockIdx.x * 256 + threadIdx.x;
    if (gid >= NPAIR * NN) return;
    int p = gid >> 11, i = gid & (NN - 1);
    int b = p >> 2, k = p & 3;
    const float* pcr = pc + ((size_t)b * NN + i) * 3;
    const float* al  = alphas + k * 3;
    float x = pcr[0] * al[0], y = pcr[1] * al[1], z = pcr[2] * al[2];
    float q = CWF * (x * x + y * y + z * z);
    float4 o; o.x = x; o.y = y; o.z = z; o.w = q;
    ((float4*)Xs)[gid] = o;
    _Float16* xt = XT + (size_t)p * 16 * NN + i;
    xt[0 * NN] = (_Float16)x;
    xt[1 * NN] = (_Float16)y;
    xt[2 * NN] = (_Float16)z;
    xt[3 * NN] = (_Float16)1.0f;
#pragma unroll
    for (int n = 4; n < 16; ++n) xt[n * NN] = (_Float16)0.f;
    // packed entry e = i>>1, half-slot par = i&1: {x2,y2,z2,q2}
    _Float16* xp = Xp + ((size_t)p * 1024 + (i >> 1)) * 8 + (i & 1);
    xp[0] = (_Float16)x; xp[2] = (_Float16)y;
    xp[4] = (_Float16)z; xp[6] = (_Float16)q;
}

// ---- fused apply (R14 body): out = f16(0.5*cur + ihd (x) (W@cur^T)^T).
// 512 thr = 8 K-waves (chunk 256); lane: s=2 m-subtiles; M=32; grid (64,16).
// DUAL: one shared w-eval pass feeds two banks' MFMAs (cur1/out1 + cur2/out2).
template<bool FIRST, bool DUAL>
__global__ __launch_bounds__(512, DUAL ? 4 : 8)
void apply_k(const float* __restrict__ Xs, const _Float16* __restrict__ Xp,
             float* __restrict__ ihd,
             const _Float16* __restrict__ cur1, _Float16* __restrict__ out1,
             float* __restrict__ lvl1, int t1,
             const _Float16* __restrict__ cur2, _Float16* __restrict__ out2,
             float* __restrict__ lvl2, int t2) {
    __shared__ __align__(16) float smem[4096];     // 16 KB: X stage / red alias
    const int tid  = threadIdx.x;
    const int lane = tid & 63;
    const int wv   = tid >> 6;                     // K-group 0..7
    const int p    = blockIdx.y;
    const int m0   = blockIdx.x * 32;
    const int idx16 = lane & 15, quad = lane >> 4;

    {
        const float4* src = (const float4*)(Xp + (size_t)p * 8192);
        float4* dst = (float4*)smem;
        dst[tid]       = src[tid];
        dst[tid + 512] = src[tid + 512];
    }
    __syncthreads();

    f16x2 qi2[2], xx2[2], xy2[2], xz2[2];
#pragma unroll
    for (int s = 0; s < 2; ++s) {
        float4 v = *(const float4*)(Xs + ((size_t)p * NN + m0 + s * 16 + idx16) * 4);
        _Float16 q = (_Float16)(v.w + NL2T);
        _Float16 x = (_Float16)(C2F * v.x);
        _Float16 y = (_Float16)(C2F * v.y);
        _Float16 z = (_Float16)(C2F * v.z);
        qi2[s] = (f16x2){q, q}; xx2[s] = (f16x2){x, x};
        xy2[s] = (f16x2){y, y}; xz2[s] = (f16x2){z, z};
    }
    const f16x2 SC2 = (f16x2){(_Float16)32768.f, (_Float16)32768.f};

    const _Float16* bp1 = cur1 + ((size_t)p * 16 + idx16) * NN + wv * 256 + quad * 8;
    const _Float16* bp2 = DUAL ? cur2 + ((size_t)p * 16 + idx16) * NN + wv * 256 + quad * 8
                               : nullptr;
    f32x4 acc1[2] = {{0.f,0.f,0.f,0.f},{0.f,0.f,0.f,0.f}};
    f32x4 acc2[2] = {{0.f,0.f,0.f,0.f},{0.f,0.f,0.f,0.f}};

    for (int kc = 0; kc < 8; ++kc) {
        const int pb = wv * 128 + kc * 16 + quad * 4;  // j-pair entry base
        half8 bf1 = *(const half8*)(bp1 + kc * 32);
        half8 bf2;
        if (DUAL) bf2 = *(const half8*)(bp2 + kc * 32);
        union { f16x2 h2[4]; half8 h8; } af[2];
#pragma unroll
        for (int jp = 0; jp < 4; ++jp) {
            union { float4 f; f16x2 h[4]; } e;
            e.f = ((const float4*)smem)[pb + jp];      // {x2,y2,z2,q2} for 2 j
#pragma unroll
            for (int s = 0; s < 2; ++s) {
                f16x2 tv = qi2[s] + e.h[3];
                tv = __builtin_elementwise_fma(xx2[s], e.h[0], tv);
                tv = __builtin_elementwise_fma(xy2[s], e.h[1], tv);
                tv = __builtin_elementwise_fma(xz2[s], e.h[2], tv);
                // threshold folded into exp arg: t'<0 -> arg<=-24 -> exp2 = 0
                f16x2 u = __builtin_elementwise_min(tv, tv * SC2);
                af[s].h2[jp] = __ocml_exp2_2f16(u);    // = 10*w (2^3.32 fold)
            }
        }
#pragma unroll
        for (int s = 0; s < 2; ++s) {
            acc1[s] = __builtin_amdgcn_mfma_f32_16x16x32_f16(af[s].h8, bf1, acc1[s], 0, 0, 0);
            if (DUAL)
                acc2[s] = __builtin_amdgcn_mfma_f32_16x16x32_f16(af[s].h8, bf2, acc2[s], 0, 0, 0);
        }
    }

    // epilogue (R14-proven mapping); one output/thread per bank pass
    const int n = tid & 15, rloc = tid >> 4;
    const int s2 = rloc >> 4, mloc = rloc & 15;
    const int base = s2 * 256 + (mloc >> 2) * 64 + (mloc & 3);
    const int row = m0 + rloc;
    float ihEff;
    if (!FIRST) ihEff = 0.1f * ihd[p * NN + row];

    // bank 1 pass
    __syncthreads();
#pragma unroll
    for (int s = 0; s < 2; ++s)
        *(f32x4*)&smem[wv * 512 + s * 256 + lane * 4] = acc1[s];
    __syncthreads();
    {
        float sum = 0.f;                               // = 10*(W@B)
#pragma unroll
        for (int g = 0; g < 8; ++g) sum += smem[g * 512 + base + n * 4];
        if (FIRST) {
            float deg10 = 0.f;                         // = 10*deg
#pragma unroll
            for (int g = 0; g < 8; ++g) deg10 += smem[g * 512 + base + 12];
            float ih = 5.0f / deg10;                   // = 0.5/deg
            if (n == 3) ihd[p * NN + row] = ih;
            ihEff = 0.1f * ih;
        }
        float cv = (float)cur1[((size_t)p * 16 + n) * NN + row];
        float o = 0.5f * cv + ihEff * sum;
        out1[((size_t)p * 16 + n) * NN + row] = (_Float16)o;
        if (lvl1) lvl1[(((size_t)p * 5 + t1) * 16 + n) * NN + row] = o;
    }
    if (DUAL) {
        __syncthreads();
#pragma unroll
        for (int s = 0; s < 2; ++s)
            *(f32x4*)&smem[wv * 512 + s * 256 + lane * 4] = acc2[s];
        __syncthreads();
        float sum = 0.f;
#pragma unroll
        for (int g = 0; g < 8; ++g) sum += smem[g * 512 + base + n * 4];
        float cv = (float)cur2[((size_t)p * 16 + n) * NN + row];
        float o = 0.5f * cv + ihEff * sum;
        out2[((size_t)p * 16 + n) * NN + row] = (_Float16)o;
        if (lvl2) lvl2[(((size_t)p * 5 + t2) * 16 + n) * NN + row] = o;
    }
}

// ---- build UT fp16 [p][16][2048]: rows 0-11 = |psi_0..3 X|, 12-15 = 0 ----
__global__ __launch_bounds__(256) void buildU_k(const float* __restrict__ Xs,
                                                const float* __restrict__ LT1,
                                                _Float16* __restrict__ UT) {
    int p = blockIdx.y;
    int m = blockIdx.x * 256 + threadIdx.x;
    const float* lp = LT1 + (size_t)p * 5 * 16 * NN;
    float4 xr = ((const float4*)Xs)[p * NN + m];
    float prev[3] = {xr.x, xr.y, xr.z};
    _Float16* ut = UT + (size_t)p * 16 * NN + m;
#pragma unroll
    for (int jw = 0; jw < 4; ++jw) {
#pragma unroll
        for (int c = 0; c < 3; ++c) {
            float nx = lp[((size_t)jw * 16 + c) * NN + m];
            ut[(3 * jw + c) * NN] = (_Float16)fabsf(prev[c] - nx);
            prev[c] = nx;
        }
    }
#pragma unroll
    for (int n = 12; n < 16; ++n) ut[n * NN] = (_Float16)0.f;
}

// ---- final mean over N of 48 features (levels [p][t][n][m]) ----
__global__ __launch_bounds__(64) void reduce_k(const float* __restrict__ Xs,
                                               const float* __restrict__ LT1,
                                               const float* __restrict__ LT2,
                                               float* __restrict__ out) {
    int f = blockIdx.x, p = blockIdx.y, lane = threadIdx.x;
    const float* l1 = LT1 + (size_t)p * 5 * 16 * NN;
    const float* l2 = LT2 + (size_t)p * 5 * 16 * NN;
    float s = 0.f;
    for (int m = lane; m < NN; m += 64) {
        float v;
        if (f < 3) {
            v = l1[((size_t)4 * 16 + f) * NN + m];
        } else if (f < 18) {
            int j = (f - 3) / 3, c = (f - 3) % 3;
            float a = (j == 0) ? Xs[((size_t)p * NN + m) * 4 + c]
                               : l1[((size_t)(j - 1) * 16 + c) * NN + m];
            float b = l1[((size_t)j * 16 + c) * NN + m];
            v = fabsf(a - b);
        } else {
            int gg = f - 18, j2, uc;
            if (gg < 3)       { j2 = 1; uc = gg; }
            else if (gg < 9)  { j2 = 2; uc = gg - 3; }
            else if (gg < 18) { j2 = 3; uc = gg - 9; }
            else              { j2 = 4; uc = gg - 18; }
            v = fabsf(l2[((size_t)(j2 - 1) * 16 + uc) * NN + m]
                    - l2[((size_t)j2 * 16 + uc) * NN + m]);
        }
        s += v;
    }
#pragma unroll
    for (int off = 32; off > 0; off >>= 1) s += __shfl_down(s, off, 64);
    if (lane == 0) out[p * 48 + f] = s * (1.0f / NN);
}

extern "C" void kernel_launch(void* const* d_in, const int* in_sizes, int n_in,
                              void* d_out, int out_size, void* d_ws, size_t ws_size,
                              hipStream_t stream) {
    const float* pc     = (const float*)d_in[0];
    const float* alphas = (const float*)d_in[1];
    float* outp = (float*)d_out;

    char* base = (char*)d_ws;
    size_t off = 0;
    auto carve = [&](size_t bytes) -> void* {
        void* r = base + off;
        off = (off + bytes + 255) & ~(size_t)255;
        return r;
    };
    float*     Xs  = (float*)carve((size_t)NPAIR * NN * 4 * sizeof(float));
    _Float16*  Xp  = (_Float16*)carve((size_t)NPAIR * 1024 * 8 * 2);
    float*     ihd = (float*)carve((size_t)NPAIR * NN * sizeof(float));
    _Float16*  XT  = (_Float16*)carve((size_t)NPAIR * 16 * NN * 2);
    _Float16*  UT  = (_Float16*)carve((size_t)NPAIR * 16 * NN * 2);
    _Float16*  pA  = (_Float16*)carve((size_t)NPAIR * 16 * NN * 2);
    _Float16*  pB  = (_Float16*)carve((size_t)NPAIR * 16 * NN * 2);
    _Float16*  pC  = (_Float16*)carve((size_t)NPAIR * 16 * NN * 2);
    _Float16*  pD  = (_Float16*)carve((size_t)NPAIR * 16 * NN * 2);
    float*     LT1 = (float*)carve((size_t)NPAIR * 5 * 16 * NN * sizeof(float));
    float*     LT2 = (float*)carve((size_t)NPAIR * 5 * 16 * NN * sizeof(float));

    dim3 gridA(NN / 32, NPAIR);   // 64 x 16 = 1024 blocks

    initpack_k<<<dim3((NPAIR * NN) / 256), 256, 0, stream>>>(pc, alphas, Xs, XT, Xp);

    // phase 1: bank1 steps 1..8 (saves t=1,2,4,8 -> LT1 slots 0..3)
    const _Float16* c1 = XT;
    int slot = 0;
    for (int step = 1; step <= 8; ++step) {
        _Float16* o1 = (c1 == pA) ? pB : pA;
        bool sv = (step & (step - 1)) == 0;
        float* lv = sv ? LT1 : nullptr;
        if (step == 1)
            apply_k<true, false><<<gridA, 512, 0, stream>>>(Xs, Xp, ihd,
                c1, o1, lv, slot, nullptr, nullptr, nullptr, 0);
        else
            apply_k<false, false><<<gridA, 512, 0, stream>>>(Xs, Xp, ihd,
                c1, o1, lv, slot, nullptr, nullptr, nullptr, 0);
        if (sv) ++slot;
        c1 = o1;
    }

    buildU_k<<<dim3(NN / 256, NPAIR), 256, 0, stream>>>(Xs, LT1, UT);

    // phase 2: merged — bank1 steps 9..16 + bank2 steps 1..8 (shared evals)
    const _Float16* c2 = UT;
    int slot2 = 0;
    for (int i = 1; i <= 8; ++i) {
        _Float16* o1 = (c1 == pA) ? pB : pA;
        _Float16* o2 = (c2 == pC) ? pD : pC;
        float* lv1 = (i == 8) ? LT1 : nullptr;              // bank1 t=16 -> slot 4
        bool sv2 = (i & (i - 1)) == 0;                      // i = 1,2,4,8
        float* lv2 = sv2 ? LT2 : nullptr;
        apply_k<false, true><<<gridA, 512, 0, stream>>>(Xs, Xp, ihd,
            c1, o1, lv1, 4, c2, o2, lv2, slot2);
        if (sv2) ++slot2;
        c1 = o1; c2 = o2;
    }

    // phase 3: bank2 steps 9..16 (save t=16 -> LT2 slot 4)
    for (int i = 9; i <= 16; ++i) {
        _Float16* o2 = (c2 == pC) ? pD : pC;
        float* lv2 = (i == 16) ? LT2 : nullptr;
        apply_k<false, false><<<gridA, 512, 0, stream>>>(Xs, Xp, ihd,
            c2, o2, lv2, 4, nullptr, nullptr, nullptr, 0);
        c2 = o2;
    }

    reduce_k<<<dim3(48, NPAIR), 64, 0, stream>>>(Xs, LT1, LT2, outp);
}

// Round 19
// 482.736 us; speedup vs baseline: 3.1369x; 1.0019x over previous
//
#include <hip/hip_runtime.h>
#include <hip/hip_bf16.h>

// PointCloudNetPersistencePrediction — round 19: consolidation on R18.
// R18 confirmed boundary model (launch merge -70us as predicted). Cuts:
// (1) buildU fused into step-8 single's epilogue (block owns its U rows;
//     t=1,2,4 from LT1 global, fresh t=8 via 96-float LDS stash) -> -1 launch.
// (2) dual epilogue single-pass (32KB red: both banks side by side) -> 2
//     syncthreads instead of 4.
// Persistent-kernel lever remains dead: grid.sync ~35us (R15), DIY LLC sync
// incorrect (R16).

#define NN 2048
#define NPAIR 16

typedef _Float16 half8 __attribute__((ext_vector_type(8)));
typedef _Float16 f16x2 __attribute__((ext_vector_type(2)));
typedef float f32x4 __attribute__((ext_vector_type(4)));

extern "C" __device__ f16x2 __ocml_exp2_2f16(f16x2);   // packed v_exp_f16

#define C2F 0.28853900817779268f   //  0.2 * log2(e)
#define CWF -0.14426950408889634f  // -0.1 * log2(e)
#define NL2T 3.3219280948873623f   // -log2(0.1); qi' = qi + NL2T

// ---- init+pack fused: Xs fp32 [p][i][{x,y,z,q}]; XT fp16 [p][16][2048]
//      (row3 = ones -> deg via MFMA); Xp packed fp16 j-pair entries ----
__global__ __launch_bounds__(256) void initpack_k(const float* __restrict__ pc,
                                                  const float* __restrict__ alphas,
                                                  float* __restrict__ Xs,
                                                  _Float16* __restrict__ XT,
                                                  _Float16* __restrict__ Xp) {
    int gid = blockIdx.x * 256 + threadIdx.x;
    if (gid >= NPAIR * NN) return;
    int p = gid >> 11, i = gid & (NN - 1);
    int b = p >> 2, k = p & 3;
    const float* pcr = pc + ((size_t)b * NN + i) * 3;
    const float* al  = alphas + k * 3;
    float x = pcr[0] * al[0], y = pcr[1] * al[1], z = pcr[2] * al[2];
    float q = CWF * (x * x + y * y + z * z);
    float4 o; o.x = x; o.y = y; o.z = z; o.w = q;
    ((float4*)Xs)[gid] = o;
    _Float16* xt = XT + (size_t)p * 16 * NN + i;
    xt[0 * NN] = (_Float16)x;
    xt[1 * NN] = (_Float16)y;
    xt[2 * NN] = (_Float16)z;
    xt[3 * NN] = (_Float16)1.0f;
#pragma unroll
    for (int n = 4; n < 16; ++n) xt[n * NN] = (_Float16)0.f;
    _Float16* xp = Xp + ((size_t)p * 1024 + (i >> 1)) * 8 + (i & 1);
    xp[0] = (_Float16)x; xp[2] = (_Float16)y;
    xp[4] = (_Float16)z; xp[6] = (_Float16)q;
}

// ---- fused apply: out = f16(0.5*cur + ihd (x) (W@cur^T)^T).
// 512 thr = 8 K-waves (chunk 256); lane: s=2 m-subtiles; M=32; grid (64,16).
// DUAL: shared w-eval pass feeds two banks' MFMAs, single-pass epilogue.
// BUILDU: step-8 epilogue also emits this block's UT rows.
template<bool FIRST, bool DUAL, bool BUILDU>
__global__ __launch_bounds__(512, DUAL ? 4 : 8)
void apply_k(const float* __restrict__ Xs, const _Float16* __restrict__ Xp,
             float* __restrict__ ihd,
             const _Float16* __restrict__ cur1, _Float16* __restrict__ out1,
             float* __restrict__ lvl1, int t1,
             const _Float16* __restrict__ cur2, _Float16* __restrict__ out2,
             float* __restrict__ lvl2, int t2,
             const float* __restrict__ LT1u, _Float16* __restrict__ UTp) {
    constexpr int SMSZ = DUAL ? 8192 : 4352;       // floats
    __shared__ __align__(16) float smem[SMSZ];
    const int tid  = threadIdx.x;
    const int lane = tid & 63;
    const int wv   = tid >> 6;                     // K-group 0..7
    const int p    = blockIdx.y;
    const int m0   = blockIdx.x * 32;
    const int idx16 = lane & 15, quad = lane >> 4;

    {
        const float4* src = (const float4*)(Xp + (size_t)p * 8192);
        float4* dst = (float4*)smem;
        dst[tid]       = src[tid];
        dst[tid + 512] = src[tid + 512];
    }
    __syncthreads();

    f16x2 qi2[2], xx2[2], xy2[2], xz2[2];
#pragma unroll
    for (int s = 0; s < 2; ++s) {
        float4 v = *(const float4*)(Xs + ((size_t)p * NN + m0 + s * 16 + idx16) * 4);
        _Float16 q = (_Float16)(v.w + NL2T);
        _Float16 x = (_Float16)(C2F * v.x);
        _Float16 y = (_Float16)(C2F * v.y);
        _Float16 z = (_Float16)(C2F * v.z);
        qi2[s] = (f16x2){q, q}; xx2[s] = (f16x2){x, x};
        xy2[s] = (f16x2){y, y}; xz2[s] = (f16x2){z, z};
    }
    const f16x2 SC2 = (f16x2){(_Float16)32768.f, (_Float16)32768.f};

    const _Float16* bp1 = cur1 + ((size_t)p * 16 + idx16) * NN + wv * 256 + quad * 8;
    const _Float16* bp2 = DUAL ? cur2 + ((size_t)p * 16 + idx16) * NN + wv * 256 + quad * 8
                               : nullptr;
    f32x4 acc1[2] = {{0.f,0.f,0.f,0.f},{0.f,0.f,0.f,0.f}};
    f32x4 acc2[2] = {{0.f,0.f,0.f,0.f},{0.f,0.f,0.f,0.f}};

    for (int kc = 0; kc < 8; ++kc) {
        const int pb = wv * 128 + kc * 16 + quad * 4;  // j-pair entry base
        half8 bf1 = *(const half8*)(bp1 + kc * 32);
        half8 bf2;
        if (DUAL) bf2 = *(const half8*)(bp2 + kc * 32);
        union { f16x2 h2[4]; half8 h8; } af[2];
#pragma unroll
        for (int jp = 0; jp < 4; ++jp) {
            union { float4 f; f16x2 h[4]; } e;
            e.f = ((const float4*)smem)[pb + jp];      // {x2,y2,z2,q2} for 2 j
#pragma unroll
            for (int s = 0; s < 2; ++s) {
                f16x2 tv = qi2[s] + e.h[3];
                tv = __builtin_elementwise_fma(xx2[s], e.h[0], tv);
                tv = __builtin_elementwise_fma(xy2[s], e.h[1], tv);
                tv = __builtin_elementwise_fma(xz2[s], e.h[2], tv);
                // threshold folded into exp arg: t'<0 -> arg<=-24 -> exp2 = 0
                f16x2 u = __builtin_elementwise_min(tv, tv * SC2);
                af[s].h2[jp] = __ocml_exp2_2f16(u);    // = 10*w (2^3.32 fold)
            }
        }
#pragma unroll
        for (int s = 0; s < 2; ++s) {
            acc1[s] = __builtin_amdgcn_mfma_f32_16x16x32_f16(af[s].h8, bf1, acc1[s], 0, 0, 0);
            if (DUAL)
                acc2[s] = __builtin_amdgcn_mfma_f32_16x16x32_f16(af[s].h8, bf2, acc2[s], 0, 0, 0);
        }
    }

    // ---- epilogue ----
    const int n = tid & 15, rloc = tid >> 4;
    const int s2 = rloc >> 4, mloc = rloc & 15;
    const int base = s2 * 256 + (mloc >> 2) * 64 + (mloc & 3);
    const int row = m0 + rloc;
    float ihEff;
    if (!FIRST) ihEff = 0.1f * ihd[p * NN + row];

    __syncthreads();
#pragma unroll
    for (int s = 0; s < 2; ++s)
        *(f32x4*)&smem[wv * 512 + s * 256 + lane * 4] = acc1[s];
    if (DUAL) {
#pragma unroll
        for (int s = 0; s < 2; ++s)
            *(f32x4*)&smem[4096 + wv * 512 + s * 256 + lane * 4] = acc2[s];
    }
    __syncthreads();

    float o1v;
    {
        float sum = 0.f;                               // = 10*(W@B)
#pragma unroll
        for (int g = 0; g < 8; ++g) sum += smem[g * 512 + base + n * 4];
        if (FIRST) {
            float deg10 = 0.f;                         // = 10*deg
#pragma unroll
            for (int g = 0; g < 8; ++g) deg10 += smem[g * 512 + base + 12];
            float ih = 5.0f / deg10;                   // = 0.5/deg
            if (n == 3) ihd[p * NN + row] = ih;
            ihEff = 0.1f * ih;
        }
        float cv = (float)cur1[((size_t)p * 16 + n) * NN + row];
        o1v = 0.5f * cv + ihEff * sum;
        out1[((size_t)p * 16 + n) * NN + row] = (_Float16)o1v;
        if (lvl1) lvl1[(((size_t)p * 5 + t1) * 16 + n) * NN + row] = o1v;
    }
    if (DUAL) {
        float sum = 0.f;
#pragma unroll
        for (int g = 0; g < 8; ++g) sum += smem[4096 + g * 512 + base + n * 4];
        float cv = (float)cur2[((size_t)p * 16 + n) * NN + row];
        float o = 0.5f * cv + ihEff * sum;
        out2[((size_t)p * 16 + n) * NN + row] = (_Float16)o;
        if (lvl2) lvl2[(((size_t)p * 5 + t2) * 16 + n) * NN + row] = o;
    }
    if (BUILDU) {
        // stash fresh t=8 (cols 0-2) then emit this block's UT rows
        if (n < 3) smem[4096 + n * 32 + rloc] = o1v;
        __syncthreads();
        _Float16 uv = (_Float16)0.f;
        if (n < 12) {
            const int jw = n / 3, c = n - 3 * jw;
            float a = (jw == 0) ? Xs[((size_t)p * NN + row) * 4 + c]
                                : LT1u[(((size_t)p * 5 + (jw - 1)) * 16 + c) * NN + row];
            float bb = (jw == 3) ? smem[4096 + c * 32 + rloc]
                                 : LT1u[(((size_t)p * 5 + jw) * 16 + c) * NN + row];
            uv = (_Float16)fabsf(a - bb);
        }
        UTp[((size_t)p * 16 + n) * NN + row] = uv;
    }
}

// ---- final mean over N of 48 features (levels [p][t][n][m]) ----
__global__ __launch_bounds__(64) void reduce_k(const float* __restrict__ Xs,
                                               const float* __restrict__ LT1,
                                               const float* __restrict__ LT2,
                                               float* __restrict__ out) {
    int f = blockIdx.x, p = blockIdx.y, lane = threadIdx.x;
    const float* l1 = LT1 + (size_t)p * 5 * 16 * NN;
    const float* l2 = LT2 + (size_t)p * 5 * 16 * NN;
    float s = 0.f;
    for (int m = lane; m < NN; m += 64) {
        float v;
        if (f < 3) {
            v = l1[((size_t)4 * 16 + f) * NN + m];
        } else if (f < 18) {
            int j = (f - 3) / 3, c = (f - 3) % 3;
            float a = (j == 0) ? Xs[((size_t)p * NN + m) * 4 + c]
                               : l1[((size_t)(j - 1) * 16 + c) * NN + m];
            float b = l1[((size_t)j * 16 + c) * NN + m];
            v = fabsf(a - b);
        } else {
            int gg = f - 18, j2, uc;
            if (gg < 3)       { j2 = 1; uc = gg; }
            else if (gg < 9)  { j2 = 2; uc = gg - 3; }
            else if (gg < 18) { j2 = 3; uc = gg - 9; }
            else              { j2 = 4; uc = gg - 18; }
            v = fabsf(l2[((size_t)(j2 - 1) * 16 + uc) * NN + m]
                    - l2[((size_t)j2 * 16 + uc) * NN + m]);
        }
        s += v;
    }
#pragma unroll
    for (int off = 32; off > 0; off >>= 1) s += __shfl_down(s, off, 64);
    if (lane == 0) out[p * 48 + f] = s * (1.0f / NN);
}

extern "C" void kernel_launch(void* const* d_in, const int* in_sizes, int n_in,
                              void* d_out, int out_size, void* d_ws, size_t ws_size,
                              hipStream_t stream) {
    const float* pc     = (const float*)d_in[0];
    const float* alphas = (const float*)d_in[1];
    float* outp = (float*)d_out;

    char* base = (char*)d_ws;
    size_t off = 0;
    auto carve = [&](size_t bytes) -> void* {
        void* r = base + off;
        off = (off + bytes + 255) & ~(size_t)255;
        return r;
    };
    float*     Xs  = (float*)carve((size_t)NPAIR * NN * 4 * sizeof(float));
    _Float16*  Xp  = (_Float16*)carve((size_t)NPAIR * 1024 * 8 * 2);
    float*     ihd = (float*)carve((size_t)NPAIR * NN * sizeof(float));
    _Float16*  XT  = (_Float16*)carve((size_t)NPAIR * 16 * NN * 2);
    _Float16*  UT  = (_Float16*)carve((size_t)NPAIR * 16 * NN * 2);
    _Float16*  pA  = (_Float16*)carve((size_t)NPAIR * 16 * NN * 2);
    _Float16*  pB  = (_Float16*)carve((size_t)NPAIR * 16 * NN * 2);
    _Float16*  pC  = (_Float16*)carve((size_t)NPAIR * 16 * NN * 2);
    _Float16*  pD  = (_Float16*)carve((size_t)NPAIR * 16 * NN * 2);
    float*     LT1 = (float*)carve((size_t)NPAIR * 5 * 16 * NN * sizeof(float));
    float*     LT2 = (float*)carve((size_t)NPAIR * 5 * 16 * NN * sizeof(float));

    dim3 gridA(NN / 32, NPAIR);   // 64 x 16 = 1024 blocks

    initpack_k<<<dim3((NPAIR * NN) / 256), 256, 0, stream>>>(pc, alphas, Xs, XT, Xp);

    // phase 1: bank1 steps 1..8 (saves t=1,2,4,8 -> LT1 slots 0..3);
    // step 8 also emits UT (fused buildU).
    const _Float16* c1 = XT;
    int slot = 0;
    for (int step = 1; step <= 8; ++step) {
        _Float16* o1 = (c1 == pA) ? pB : pA;
        bool sv = (step & (step - 1)) == 0;
        float* lv = sv ? LT1 : nullptr;
        if (step == 1)
            apply_k<true, false, false><<<gridA, 512, 0, stream>>>(Xs, Xp, ihd,
                c1, o1, lv, slot, nullptr, nullptr, nullptr, 0, nullptr, nullptr);
        else if (step == 8)
            apply_k<false, false, true><<<gridA, 512, 0, stream>>>(Xs, Xp, ihd,
                c1, o1, lv, slot, nullptr, nullptr, nullptr, 0, LT1, UT);
        else
            apply_k<false, false, false><<<gridA, 512, 0, stream>>>(Xs, Xp, ihd,
                c1, o1, lv, slot, nullptr, nullptr, nullptr, 0, nullptr, nullptr);
        if (sv) ++slot;
        c1 = o1;
    }

    // phase 2: merged — bank1 steps 9..16 + bank2 steps 1..8 (shared evals)
    const _Float16* c2 = UT;
    int slot2 = 0;
    for (int i = 1; i <= 8; ++i) {
        _Float16* o1 = (c1 == pA) ? pB : pA;
        _Float16* o2 = (c2 == pC) ? pD : pC;
        float* lv1 = (i == 8) ? LT1 : nullptr;              // bank1 t=16 -> slot 4
        bool sv2 = (i & (i - 1)) == 0;                      // i = 1,2,4,8
        float* lv2 = sv2 ? LT2 : nullptr;
        apply_k<false, true, false><<<gridA, 512, 0, stream>>>(Xs, Xp, ihd,
            c1, o1, lv1, 4, c2, o2, lv2, slot2, nullptr, nullptr);
        if (sv2) ++slot2;
        c1 = o1; c2 = o2;
    }

    // phase 3: bank2 steps 9..16 (save t=16 -> LT2 slot 4)
    for (int i = 9; i <= 16; ++i) {
        _Float16* o2 = (c2 == pC) ? pD : pC;
        float* lv2 = (i == 16) ? LT2 : nullptr;
        apply_k<false, false, false><<<gridA, 512, 0, stream>>>(Xs, Xp, ihd,
            c2, o2, lv2, 4, nullptr, nullptr, nullptr, 0, nullptr, nullptr);
        c2 = o2;
    }

    reduce_k<<<dim3(48, NPAIR), 64, 0, stream>>>(Xs, LT1, LT2, outp);
}